// Round 3
// baseline (395.130 us; speedup 1.0000x reference)
//
#include <hip/hip_runtime.h>
#include <stdint.h>

#define EPSF 1e-20f

typedef __attribute__((ext_vector_type(4))) int i32x4;
typedef __attribute__((ext_vector_type(16))) int i32x16;

// ===========================================================================
// Pass 1: fp32 -> ±1 int8 (0x01 / 0xFF), x and w fused into one launch.
// 2048 float4 per block (8 per thread) for load ILP.
// ===========================================================================
__global__ __launch_bounds__(256)
void bin_i8_kernel(const float4* __restrict__ xsrc, const float4* __restrict__ wsrc,
                   uint32_t* __restrict__ xdst, uint32_t* __restrict__ wdst,
                   int nblk_x) {
    const float4* src;
    uint32_t* dst;
    int base;
    if (blockIdx.x < (unsigned)nblk_x) {
        src = xsrc; dst = xdst; base = blockIdx.x * 2048 + threadIdx.x;
    } else {
        src = wsrc; dst = wdst; base = (blockIdx.x - nblk_x) * 2048 + threadIdx.x;
    }
#pragma unroll
    for (int j = 0; j < 8; ++j) {
        int idx = base + j * 256;
        float4 v = src[idx];
        uint32_t b0 = (v.x < -EPSF) ? 0xFFu : 0x01u;
        uint32_t b1 = (v.y < -EPSF) ? 0xFFu : 0x01u;
        uint32_t b2 = (v.z < -EPSF) ? 0xFFu : 0x01u;
        uint32_t b3 = (v.w < -EPSF) ? 0xFFu : 0x01u;
        dst[idx] = b0 | (b1 << 8) | (b2 << 16) | (b3 << 24);
    }
}

// ===========================================================================
// Pass 2: i8 MFMA GEMM. Block tile 256x128 (BK=128B), 4 waves, each wave
// computes 64x128 via 2x4 tiles of 32x32 -> LDS reads = 0.75 KB/MFMA
// (was 1.0 at 2x2), balancing the LDS pipe (~60us) with MFMA (~62us).
// XOR chunk swizzle (slot q holds global chunk q^(row&7)) keeps
// global_load_lds coalescing (permutation within a 128B line) and makes
// compute-side ds_read_b128 conflict-free in every 8-lane phase group.
// ===========================================================================
#define GM 256
#define GN 128
#define GKB 128

__global__ __launch_bounds__(256, 2)
void i8mfma_gemm(const char* __restrict__ xi8, const char* __restrict__ wi8,
                 float* __restrict__ out) {
    __shared__ char xs[GM * GKB];    // 32 KB
    __shared__ char wsh[GN * GKB];   // 16 KB

    const int t = threadIdx.x;
    const int lane = t & 63;
    const int wave = t >> 6;
    const int lrow = lane & 31;
    const int half = lane >> 5;
    const int row0 = blockIdx.y * GM;
    const int col0 = blockIdx.x * GN;
    const int wm = wave * 64;        // wave's 64-row band

    i32x16 acc[2][4];
#pragma unroll
    for (int r = 0; r < 2; ++r)
#pragma unroll
        for (int c = 0; c < 4; ++c)
#pragma unroll
            for (int e = 0; e < 16; ++e) acc[r][c][e] = 0;

    for (int kc = 0; kc < 4096; kc += GKB) {
        __syncthreads();
        // stage xs: 2048 16B-chunks, 8 per thread
#pragma unroll
        for (int j = 0; j < 8; ++j) {
            int c = j * 256 + t;
            int row = c >> 3;
            int qg = (c & 7) ^ (row & 7);
            __builtin_amdgcn_global_load_lds(
                (const uint32_t*)(xi8 + (size_t)(row0 + row) * 4096 + kc + qg * 16),
                (uint32_t*)(xs + c * 16), 16, 0, 0);
        }
        // stage wsh: 1024 chunks, 4 per thread
#pragma unroll
        for (int j = 0; j < 4; ++j) {
            int c = j * 256 + t;
            int row = c >> 3;
            int qg = (c & 7) ^ (row & 7);
            __builtin_amdgcn_global_load_lds(
                (const uint32_t*)(wi8 + (size_t)(col0 + row) * 4096 + kc + qg * 16),
                (uint32_t*)(wsh + c * 16), 16, 0, 0);
        }
        __syncthreads();

#pragma unroll
        for (int s = 0; s < 4; ++s) {
            int g = 2 * s + half;          // 16B k-chunk for this lane-half
            i32x4 a[2], b[4];
#pragma unroll
            for (int r = 0; r < 2; ++r) {
                int row = wm + r * 32 + lrow;
                int qs = g ^ (row & 7);
                a[r] = *(const i32x4*)(xs + row * GKB + qs * 16);
            }
#pragma unroll
            for (int c = 0; c < 4; ++c) {
                int col = c * 32 + lrow;
                int qs = g ^ (col & 7);
                b[c] = *(const i32x4*)(wsh + col * GKB + qs * 16);
            }
#pragma unroll
            for (int r = 0; r < 2; ++r)
#pragma unroll
                for (int c = 0; c < 4; ++c)
                    acc[r][c] = __builtin_amdgcn_mfma_i32_32x32x32_i8(
                        a[r], b[c], acc[r][c], 0, 0, 0);
        }
    }

    // C/D 32x32 layout: col = lane&31, row = (e&3) + 8*(e>>2) + 4*(lane>>5)
#pragma unroll
    for (int r = 0; r < 2; ++r)
#pragma unroll
        for (int c = 0; c < 4; ++c)
#pragma unroll
            for (int e = 0; e < 16; ++e) {
                int rr = row0 + wm + r * 32 + (e & 3) + 8 * (e >> 2) + 4 * half;
                int cc = col0 + c * 32 + lrow;
                out[(size_t)rr * 4096 + cc] = (float)acc[r][c][e];
            }
}

// ===========================================================================
// PATH B fallback (ws too small): R1 verified bit-pack + popcount (503 us).
// ===========================================================================
__global__ __launch_bounds__(256)
void binarize_kernel(const float* __restrict__ src,
                     unsigned long long* __restrict__ dst, int n256) {
    int wave = blockIdx.x * 4 + (threadIdx.x >> 6);
    if (wave >= n256) return;
    int lane = threadIdx.x & 63;
    const float4* p = (const float4*)(src + (size_t)wave * 256);
    float4 v = p[lane];
    unsigned long long m0 = __ballot(v.x < -EPSF);
    unsigned long long m1 = __ballot(v.y < -EPSF);
    unsigned long long m2 = __ballot(v.z < -EPSF);
    unsigned long long m3 = __ballot(v.w < -EPSF);
    if (lane < 4) {
        unsigned long long m = (lane == 0) ? m0 : (lane == 1) ? m1
                             : (lane == 2) ? m2 : m3;
        dst[(size_t)wave * 4 + lane] = m;
    }
}

#define BM 128
#define BN 128
#define LDSS 9

__global__ __launch_bounds__(256, 2)
void bingemm_kernel(const uint4* __restrict__ xb, const uint4* __restrict__ wb,
                    float* __restrict__ out) {
    __shared__ uint4 xsl[BM * LDSS];
    __shared__ uint4 wsl[BN * LDSS];
    const int t = threadIdx.x, tx = t & 15, ty = t >> 4;
    const int row0 = blockIdx.y * BM, col0 = blockIdx.x * BN;
    int acc[8][8];
#pragma unroll
    for (int a = 0; a < 8; ++a)
#pragma unroll
        for (int b = 0; b < 8; ++b) acc[a][b] = 0;
    const int srow = t >> 3, sq = t & 7;
    for (int c = 0; c < 4; ++c) {
        __syncthreads();
#pragma unroll
        for (int k = 0; k < 4; ++k) {
            int r = srow + 32 * k;
            xsl[r * LDSS + sq] = xb[(size_t)(row0 + r) * 32 + c * 8 + sq];
            wsl[r * LDSS + sq] = wb[(size_t)(col0 + r) * 32 + c * 8 + sq];
        }
        __syncthreads();
#pragma unroll
        for (int q = 0; q < 8; ++q) {
            uint4 xq[8], wq[8];
#pragma unroll
            for (int ri = 0; ri < 8; ++ri) xq[ri] = xsl[(ty + 16 * ri) * LDSS + q];
#pragma unroll
            for (int cj = 0; cj < 8; ++cj) wq[cj] = wsl[(tx + 16 * cj) * LDSS + q];
#pragma unroll
            for (int ri = 0; ri < 8; ++ri)
#pragma unroll
                for (int cj = 0; cj < 8; ++cj) {
                    acc[ri][cj] += __builtin_popcount(xq[ri].x ^ wq[cj].x);
                    acc[ri][cj] += __builtin_popcount(xq[ri].y ^ wq[cj].y);
                    acc[ri][cj] += __builtin_popcount(xq[ri].z ^ wq[cj].z);
                    acc[ri][cj] += __builtin_popcount(xq[ri].w ^ wq[cj].w);
                }
        }
    }
#pragma unroll
    for (int ri = 0; ri < 8; ++ri) {
        size_t i = row0 + ty + 16 * ri;
#pragma unroll
        for (int cj = 0; cj < 8; ++cj)
            out[i * 4096 + col0 + tx + 16 * cj] = (float)(4096 - 2 * acc[ri][cj]);
    }
}

// ===========================================================================
extern "C" void kernel_launch(void* const* d_in, const int* in_sizes, int n_in,
                              void* d_out, int out_size, void* d_ws, size_t ws_size,
                              hipStream_t stream) {
    const float* x = (const float*)d_in[0];   // [8192, 4096] fp32
    const float* w = (const float*)d_in[1];   // [4096, 4096] fp32
    float* out = (float*)d_out;

    const int M = 8192, N = 4096, K = 4096;
    const size_t need_i8 = (size_t)M * K + (size_t)N * K;  // 50.3 MB

    if (ws_size >= need_i8) {
        char* xi8 = (char*)d_ws;
        char* wi8 = xi8 + (size_t)M * K;

        int nblk_x = (M * K) / (4 * 2048);          // 4096
        int nblk_w = (N * K) / (4 * 2048);          // 2048
        bin_i8_kernel<<<nblk_x + nblk_w, 256, 0, stream>>>(
            (const float4*)x, (const float4*)w,
            (uint32_t*)xi8, (uint32_t*)wi8, nblk_x);

        dim3 grid(N / GN, M / GM);                  // (32, 32)
        i8mfma_gemm<<<grid, 256, 0, stream>>>(xi8, wi8, out);
    } else {
        uint32_t* xbits = (uint32_t*)d_ws;
        uint32_t* wbits = xbits + (size_t)M * (K / 32);
        binarize_kernel<<<(M * K) / 1024, 256, 0, stream>>>(
            x, (unsigned long long*)xbits, (M * K) / 256);
        binarize_kernel<<<(N * K) / 1024, 256, 0, stream>>>(
            w, (unsigned long long*)wbits, (N * K) / 256);
        dim3 grid(N / BN, M / BM);
        bingemm_kernel<<<grid, 256, 0, stream>>>(
            (const uint4*)xbits, (const uint4*)wbits, out);
    }
}